// Round 6
// baseline (306.564 us; speedup 1.0000x reference)
//
#include <hip/hip_runtime.h>
#include <math.h>

#define NB 8
#define NH 768
#define NW 768
#define NHW (NH*NW)
#define NCEN 100
#define NPIX (NB*NHW)
#define RAD 10
#define KS 21

#define SCAN_BLKS (NPIX / 4096)   // 1152 (4096 px per K1 block)
#define BLKS_PER_B (NHW / 4096)   // 144
#define CAND_BLKS 96              // bmax blocks per batch (K2 grid = 768)
#define CHUNKS 24                 // chunks per channel plane (K3)
#define CHUNK_F4 6144             // f4 per chunk = 96 KB = 32 rows
#define OUT_BLKS (NB*13*CHUNKS)   // 2496
#define BSLOT 24                  // per-K1-block list slot stride (cnt + 23 entries)
#define BCAP 23                   // per-K1-block near-px cap
#define GCAP 256                  // per-batch compacted list cap (actual M ~36)
#define FCAP 96                   // K3 row-filtered list cap (52-row window, M<=~40)

#define STORE(v, p) (*(p) = (v))

// ws layout (ints) — plain stores only, no global atomics, no init kernel.
#define OFF_MASKS 0                         // [0, 4608): per-K1-block present masks (4 words)
#define OFF_BLIST 4608                      // [4608, 32256): per-K1-block near-px sublists
#define OFF_BMAXP 32256                     // [32256, 33024): per-(b,cb) bmax partials (float bits)
#define OFF_HAS   33024                     // [33024, 33032): has_inst per batch
#define OFF_M     33032                     // [33032, 33040): compacted list size per batch
#define OFF_GLIST 33040                     // [33040, 35088): compacted per-batch lists
#define WS_INTS   35088                     // 140,352 B; u8 copy follows (NPIX bytes)

typedef float f4 __attribute__((ext_vector_type(4)));

// Normalized 21-tap Gaussian (sigma=2), precomputed; rel err ~1e-7 vs float ref.
__device__ const float g_G[KS] = {
    7.4335e-7f, 7.9919e-6f, 6.6915e-5f, 0.00043634f, 0.00221592f,
    0.00876415f, 0.02699548f, 0.06475880f, 0.12098536f, 0.17603266f,
    0.19947114f,
    0.17603266f, 0.12098536f, 0.06475880f, 0.02699548f, 0.00876415f,
    0.00221592f, 0.00043634f, 6.6915e-5f, 7.9919e-6f, 7.4335e-7f};

// Separable blur weight of mask px q on output px p (one axis), incl. reflect
// images ('reflect' excludes edge: left image exists for q>=1, right for q<=766).
__device__ __forceinline__ float wfun(int p, int q, const float* __restrict__ g) {
    int d = p - q;
    float w = 0.f;
    if (d >= -RAD && d <= RAD) w = g[d + RAD];
    int a = p + q;
    if (q > 0 && a <= RAD) w += g[a + RAD];                               // left image
    if (q < NH - 1 && a >= 2 * (NH - 1) - RAD) w += g[a - 2 * (NH - 1) + RAD]; // right image
    return w;
}

// Fast atan2: 6-term minimax atan poly on [0,1], quadrant fixup. |err| ~1e-5 rad.
__device__ __forceinline__ float fatan2(float Y, float X) {
    float ax = fabsf(X), ay = fabsf(Y);
    float mx = fmaxf(ax, ay), mn = fminf(ax, ay);
    float a = mx > 0.f ? __fdividef(mn, mx) : 0.f;
    float ss = a * a;
    float r = fmaf(fmaf(fmaf(fmaf(fmaf(-0.01172120f, ss, 0.05265332f), ss,
                -0.11643287f), ss, 0.19354346f), ss, -0.33262347f), ss, 0.99997726f) * a;
    if (ay > ax) r = 1.57079637f - r;
    if (X < 0.f) r = 3.14159274f - r;
    return copysignf(r, Y);
}

// K1: scan — per-block present masks + near-px sublists (plain stores) + u8
// compression of instances staged through LDS (1 KB/wave contiguous store).
template <bool U8>
__global__ __launch_bounds__(256) void k_scan(const int4* __restrict__ inst4,
                                              const float* __restrict__ centers,
                                              int* __restrict__ ws,
                                              unsigned char* __restrict__ u8) {
    __shared__ unsigned sm[4];
    __shared__ float2 s_c2[NCEN];
    __shared__ int s_loc[BCAP];
    __shared__ int s_lcnt;
    __shared__ unsigned s_u8[1024];
    int t = threadIdx.x;
    int blk = blockIdx.x;
    int b = blk / BLKS_PER_B;
    int lblk = blk - b * BLKS_PER_B;
    if (t < 4) sm[t] = 0;
    if (t == 0) s_lcnt = 0;
    for (int k = t; k < NCEN; k += 256)
        s_c2[k] = ((const float2*)centers)[b * NCEN + k];   // (.x=cy, .y=cx)
    __syncthreads();

    unsigned m0 = 0, m1 = 0, m2 = 0, m3 = 0;
    size_t base = (size_t)blk * 1024 + t;   // int4 units
    int ppb = lblk * 4096 + t * 4;          // px offset within batch, q=0
#pragma unroll
    for (int q = 0; q < 4; q++) {
        int4 v = inst4[base + (size_t)q * 256];
        int pp = ppb + q * 1024;
        int i = pp / NW;
        int j0 = pp - i * NW;               // 4 px never straddle a row (4|768)
        if (U8) {
            unsigned packed = ((unsigned)v.x & 255u) | (((unsigned)v.y & 255u) << 8) |
                              (((unsigned)v.z & 255u) << 16) | (((unsigned)v.w & 255u) << 24);
            s_u8[q * 256 + t] = packed;
        }
        int a[4] = {v.x, v.y, v.z, v.w};
#pragma unroll
        for (int e = 0; e < 4; e++) {
            int iv = a[e];
            if (iv > 0) {
                unsigned bit = 1u << (iv & 31);
                int w = iv >> 5;
                if (w == 0) m0 |= bit; else if (w == 1) m1 |= bit;
                else if (w == 2) m2 |= bit; else m3 |= bit;
                int idx = iv - 1;
                idx = idx > NCEN - 1 ? NCEN - 1 : idx;
                float2 c = s_c2[idx];
                if (fabsf(c.y - (float)i) < 3.f && fabsf(c.x - (float)(j0 + e)) < 3.f) {
                    int slot = atomicAdd(&s_lcnt, 1);  // LDS only
                    if (slot < BCAP) s_loc[slot] = (i << 16) | (j0 + e);
                }
            }
        }
    }
#pragma unroll
    for (int off = 32; off >= 1; off >>= 1) {
        m0 |= __shfl_xor(m0, off);
        m1 |= __shfl_xor(m1, off);
        m2 |= __shfl_xor(m2, off);
        m3 |= __shfl_xor(m3, off);
    }
    if ((t & 63) == 0) {
        if (m0) atomicOr(&sm[0], m0);
        if (m1) atomicOr(&sm[1], m1);
        if (m2) atomicOr(&sm[2], m2);
        if (m3) atomicOr(&sm[3], m3);
    }
    __syncthreads();
    if (U8) {
        int4 vv = ((const int4*)s_u8)[t];
        *(int4*)&u8[(size_t)blk * 4096 + t * 16] = vv;
    }
    if (t < 4) ws[OFF_MASKS + blk * 4 + t] = (int)sm[t];
    int cnt = s_lcnt < BCAP ? s_lcnt : BCAP;
    int* slot = &ws[OFF_BLIST + blk * BSLOT];
    if (t == 0) slot[0] = cnt;
    if (t < cnt) slot[1 + t] = s_loc[t];
}

// K2: 96 blocks/batch gather the compacted list and compute bmax partials;
// cb==0 also writes has/M/compacted list/gt_centers. Tiny latency stage.
__global__ __launch_bounds__(256) void k_bmax(const float* __restrict__ centers,
                                              int* __restrict__ ws,
                                              float* __restrict__ out) {
    __shared__ float s_g[KS];
    __shared__ int s_list[GCAP];
    __shared__ int s_tot;
    __shared__ unsigned s_m[4];
    __shared__ float s_red[4];
    int t = threadIdx.x;
    int b = blockIdx.x / CAND_BLKS;
    int cb = blockIdx.x - b * CAND_BLKS;
    if (t < KS) s_g[t] = g_G[t];
    if (t == 0) s_tot = 0;
    if (t < 4) s_m[t] = 0;
    __syncthreads();
    if (t < BLKS_PER_B) {
        const int* slot = &ws[OFF_BLIST + (b * BLKS_PER_B + t) * BSLOT];
        int cnt = slot[0];
        cnt = cnt < 0 ? 0 : (cnt > BCAP ? BCAP : cnt);
        int basep = atomicAdd(&s_tot, cnt);   // LDS; order irrelevant
        for (int i2 = 0; i2 < cnt; i2++) {
            int s = basep + i2;
            if (s < GCAP) s_list[s] = slot[1 + i2];
        }
        if (cb == 0) {
            const unsigned* pm = (const unsigned*)&ws[OFF_MASKS + (b * BLKS_PER_B + t) * 4];
            unsigned w0 = pm[0], w1 = pm[1], w2 = pm[2], w3 = pm[3];
            if (w0) atomicOr(&s_m[0], w0);
            if (w1) atomicOr(&s_m[1], w1);
            if (w2) atomicOr(&s_m[2], w2);
            if (w3) atomicOr(&s_m[3], w3);
        }
    }
    __syncthreads();
    int M = s_tot < GCAP ? s_tot : GCAP;

    if (cb == 0) {
        float* gt = out + (size_t)NB * 13 * NHW;
        if (t < NCEN) {   // gt_centers
            float vx = 0.f, vy = 0.f;
            if (t >= 1 && ((s_m[t >> 5] >> (t & 31)) & 1u)) {
                vx = centers[(b * NCEN + (t - 1)) * 2 + 1];
                vy = centers[(b * NCEN + (t - 1)) * 2 + 0];
            }
            gt[(b * NCEN + t) * 2 + 0] = vx;
            gt[(b * NCEN + t) * 2 + 1] = vy;
        }
        if (t == 0) {
            unsigned any = (s_m[0] & 0xFFFFFFFEu) | s_m[1] | s_m[2] | s_m[3];
            ws[OFF_HAS + b] = any ? 1 : 0;
            ws[OFF_M + b] = M;
        }
        for (int e = t; e < M; e += 256) ws[OFF_GLIST + b * GCAP + e] = s_list[e];
    }

    // bmax partial over M*441 candidate px (blur==0 elsewhere)
    float lmax = 0.f;
    int total = M * (KS * KS);
    for (int c = cb * 256 + t; c < total; c += CAND_BLKS * 256) {
        int m = c / (KS * KS), r = c - m * (KS * KS);
        int e = s_list[m];
        int pi = (e >> 16) + r / KS - RAD;
        int pj = (e & 0xFFFF) + (r - (r / KS) * KS) - RAD;
        if (pi < 0 || pi >= NH || pj < 0 || pj >= NW) continue;
        float acc = 0.f;
        for (int m2 = 0; m2 < M; m2++) {
            int e2 = s_list[m2];
            float wi = wfun(pi, e2 >> 16, s_g);
            if (wi == 0.f) continue;
            acc += wi * wfun(pj, e2 & 0xFFFF, s_g);
        }
        lmax = fmaxf(lmax, acc);
    }
#pragma unroll
    for (int off = 32; off >= 1; off >>= 1) lmax = fmaxf(lmax, __shfl_down(lmax, off));
    if ((t & 63) == 0) s_red[t >> 6] = lmax;
    __syncthreads();
    if (t == 0) {
        float bmx = fmaxf(fmaxf(s_red[0], s_red[1]), fmaxf(s_red[2], s_red[3]));
        ((float*)ws)[OFF_BMAXP + b * CAND_BLKS + cb] = bmx;  // plain store
    }
}

// K3: channel-major writer. Each block = one contiguous 96 KB span (32 rows)
// inside ONE channel plane -> exactly one sequential write stream per block,
// the same shape as the harness fill that sustains 6.4+ TB/s.
// blockIdx -> (b, ch, chunk); ch>=6: zeros. ch==5: sparse cmask. ch<=4: compute.
template <bool U8>
__global__ __launch_bounds__(256) void k_out(const int* __restrict__ inst,
                                             const unsigned char* __restrict__ u8,
                                             const float* __restrict__ centers,
                                             const int* __restrict__ ws,
                                             float* __restrict__ out) {
    int t = threadIdx.x;
    int blk = blockIdx.x;
    int plane = blk / CHUNKS;
    int chunk = blk - plane * CHUNKS;
    int b = plane / 13;
    int ch = plane - b * 13;
    f4* dst = (f4*)(out + (size_t)b * 13 * NHW + (size_t)ch * NHW) + chunk * CHUNK_F4;

    if (ch >= 6) {                 // zero planes: pure sequential fill
        const f4 z = {0.f, 0.f, 0.f, 0.f};
#pragma unroll
        for (int it = 0; it < CHUNK_F4 / 256; ++it) STORE(z, dst + it * 256 + t);
        return;
    }

    if (ch == 5) {                 // cmask plane: sparse blur + normalize
        __shared__ float s_g[KS];
        __shared__ int s_fl[FCAP];
        __shared__ int s_fM;
        __shared__ unsigned s_bm;
        int has = ws[OFF_HAS + b];
        int M = ws[OFF_M + b];
        if (t < KS) s_g[t] = g_G[t];
        if (t == 255) s_fM = 0;
        if (t == 254) s_bm = 0;
        __syncthreads();
        if (t < CAND_BLKS)   // reduce bmax partials (floats >= 0: uint cmp ok)
            atomicMax(&s_bm, __float_as_uint(((const float*)ws)[OFF_BMAXP + b * CAND_BLKS + t]));
        int r0 = chunk * 32;
        const int* gl = &ws[OFF_GLIST + b * GCAP];
        for (int m = t; m < M; m += 256) {
            int e = gl[m];
            int qi = e >> 16;
            // all direct + reflect contributions to rows [r0, r0+32) have
            // qi in [r0-RAD, r0+31+RAD] (reflect images only exist near the
            // matching border, which this window contains)
            if (qi >= r0 - RAD && qi < r0 + 32 + RAD) {
                int slot = atomicAdd(&s_fM, 1);
                if (slot < FCAP) s_fl[slot] = e;
            }
        }
        __syncthreads();
        int FM = s_fM < FCAP ? s_fM : FCAP;
        float sc = (has && M > 0) ? 1.f / fmaxf(__uint_as_float(s_bm), 1e-12f) : 0.f;
        for (int it = 0; it < CHUNK_F4 / 256; ++it) {
            int f = chunk * CHUNK_F4 + it * 256 + t;   // f4 idx within plane
            int p0 = f * 4;
            int gi = p0 / NW, gj0 = p0 - gi * NW;
            f4 blur = {0.f, 0.f, 0.f, 0.f};
            for (int m = 0; m < FM; m++) {
                int e2 = s_fl[m];
                float wi = wfun(gi, e2 >> 16, s_g);
                if (wi == 0.f) continue;
                int qj = e2 & 0xFFFF;
#pragma unroll
                for (int e = 0; e < 4; e++) blur[e] += wi * wfun(gj0 + e, qj, s_g);
            }
            f4 v = blur * sc;
            STORE(v, dst + it * 256 + t);
        }
        return;
    }

    // ch 0..4: per-pixel computed channel (block-uniform branch selection)
    __shared__ float2 s_c2[NCEN];
    for (int k = t; k < NCEN; k += 256)
        s_c2[k] = ((const float2*)centers)[b * NCEN + k];   // (.x=cy, .y=cx)
    int has = ws[OFF_HAS + b];
    __syncthreads();
    for (int it = 0; it < CHUNK_F4 / 256; ++it) {
        int f = chunk * CHUNK_F4 + it * 256 + t;
        int p0 = f * 4;
        int gi = p0 / NW, gj0 = p0 - gi * NW;
        int ia[4];
        if (U8) {
            unsigned v8 = *(const unsigned*)&u8[(size_t)b * NHW + p0];
            ia[0] = v8 & 255; ia[1] = (v8 >> 8) & 255;
            ia[2] = (v8 >> 16) & 255; ia[3] = v8 >> 24;
        } else {
            int4 ivv = *(const int4*)&inst[(size_t)b * NHW + p0];
            ia[0] = ivv.x; ia[1] = ivv.y; ia[2] = ivv.z; ia[3] = ivv.w;
        }
        f4 o;
#pragma unroll
        for (int e = 0; e < 4; e++) {
            int iv = ia[e];
            bool valid = iv > 0;
            int idx = iv - 1;
            idx = idx < 0 ? 0 : idx;
            float2 c = s_c2[idx];
            float gcx = valid ? c.y : -10000.f;
            float gcy = valid ? c.x : -10000.f;
            float X = gcx - (float)gi;
            float Y = gcy - (float)(gj0 + e);
            if (ch == 0) {
                o[e] = sqrtf(X * X + Y * Y) * (valid ? 1.f : 0.f);
            } else if (ch == 1) {
                o[e] = has ? fatan2(Y, X) : 0.f;
            } else if (ch == 2) {
                float R2 = X * X + Y * Y;
                float rinv = R2 > 0.f ? rsqrtf(R2) : 0.f;
                o[e] = valid ? Y * rinv : 0.f;              // sin(atan2) masked
            } else if (ch == 3) {
                float R2 = X * X + Y * Y;
                float rinv = R2 > 0.f ? rsqrtf(R2) : 0.f;
                o[e] = valid ? (R2 > 0.f ? X * rinv : 1.f) : 0.f;
            } else {
                bool near = (fabsf(X) < 3.f) && (fabsf(Y) < 3.f);
                o[e] = near ? 0.f : 1.f;    // exact for has=0 too (near=false)
            }
        }
        STORE(o, dst + it * 256 + t);
    }
}

extern "C" void kernel_launch(void* const* d_in, const int* in_sizes, int n_in,
                              void* d_out, int out_size, void* d_ws, size_t ws_size,
                              hipStream_t stream) {
    const int* inst = (const int*)d_in[0];
    const float* centers = (const float*)d_in[1];
    float* out = (float*)d_out;
    int* ws = (int*)d_ws;
    unsigned char* u8 = (unsigned char*)d_ws + (size_t)WS_INTS * 4;
    bool use_u8 = ws_size >= (size_t)WS_INTS * 4 + (size_t)NPIX;

    if (use_u8) {
        k_scan<true><<<SCAN_BLKS, 256, 0, stream>>>((const int4*)inst, centers, ws, u8);
        k_bmax<<<NB * CAND_BLKS, 256, 0, stream>>>(centers, ws, out);
        k_out<true><<<OUT_BLKS, 256, 0, stream>>>(inst, u8, centers, ws, out);
    } else {
        k_scan<false><<<SCAN_BLKS, 256, 0, stream>>>((const int4*)inst, centers, ws, u8);
        k_bmax<<<NB * CAND_BLKS, 256, 0, stream>>>(centers, ws, out);
        k_out<false><<<OUT_BLKS, 256, 0, stream>>>(inst, u8, centers, ws, out);
    }
}

// Round 7
// 270.307 us; speedup vs baseline: 1.1341x; 1.1341x over previous
//
#include <hip/hip_runtime.h>
#include <hip/hip_cooperative_groups.h>
#include <math.h>

namespace cg = cooperative_groups;

#define NB 8
#define NH 768
#define NW 768
#define NHW (NH*NW)
#define NCEN 100
#define NPIX (NB*NHW)
#define RAD 10
#define KS 21

#define SCAN_BLKS (NPIX / 4096)   // 1152 blocks, 4096 px each
#define BLKS_PER_B (NHW / 4096)   // 144
#define CAND_BLKS 96              // bmax blocks per batch (768 total)
#define ZPB 7168                  // f4 zeros per block (1152*7168 = 7ch*NB f4 exactly)
#define ZIT (ZPB/256)             // 28
#define BSLOT 24                  // per-block list slot stride (cnt + 23 entries)
#define BCAP 23                   // per-block near-px cap
#define GCAP 256                  // per-batch compacted list cap (actual M ~36)
#define FCAP 256                  // row-filtered cap (== GCAP: no overflow)

#define STORE(v, p) (*(p) = (v))

// ws layout (ints) — plain stores only, no global atomics, no init kernel.
#define OFF_MASKS 0                         // [0, 4608): per-block present masks (4 words)
#define OFF_BLIST 4608                      // [4608, 32256): per-block near-px sublists
#define OFF_BMAXP 32256                     // [32256, 33024): per-(b,cb) bmax partials
#define OFF_HAS   33024                     // [33024, 33032): has_inst per batch
#define OFF_M     33032                     // [33032, 33040): list size per batch
#define OFF_GLIST 33040                     // [33040, 35088): compacted per-batch lists

typedef float f4 __attribute__((ext_vector_type(4)));

// Normalized 21-tap Gaussian (sigma=2), precomputed; rel err ~1e-7 vs float ref.
__device__ const float g_G[KS] = {
    7.4335e-7f, 7.9919e-6f, 6.6915e-5f, 0.00043634f, 0.00221592f,
    0.00876415f, 0.02699548f, 0.06475880f, 0.12098536f, 0.17603266f,
    0.19947114f,
    0.17603266f, 0.12098536f, 0.06475880f, 0.02699548f, 0.00876415f,
    0.00221592f, 0.00043634f, 6.6915e-5f, 7.9919e-6f, 7.4335e-7f};

// Separable blur weight of mask px q on output px p (one axis), incl. reflect
// images ('reflect' excludes edge). All contributions to row p come from
// q in [p-RAD, p+RAD] (direct and reflected images both land there).
__device__ __forceinline__ float wfun(int p, int q, const float* __restrict__ g) {
    int d = p - q;
    float w = 0.f;
    if (d >= -RAD && d <= RAD) w = g[d + RAD];
    int a = p + q;
    if (q > 0 && a <= RAD) w += g[a + RAD];                               // left image
    if (q < NH - 1 && a >= 2 * (NH - 1) - RAD) w += g[a - 2 * (NH - 1) + RAD]; // right image
    return w;
}

// Fast atan2: 6-term minimax atan poly on [0,1], quadrant fixup. |err| ~1e-5 rad.
__device__ __forceinline__ float fatan2(float Y, float X) {
    float ax = fabsf(X), ay = fabsf(Y);
    float mx = fmaxf(ax, ay), mn = fminf(ax, ay);
    float a = mx > 0.f ? __fdividef(mn, mx) : 0.f;
    float ss = a * a;
    float r = fmaf(fmaf(fmaf(fmaf(fmaf(-0.01172120f, ss, 0.05265332f), ss,
                -0.11643287f), ss, 0.19354346f), ss, -0.33262347f), ss, 0.99997726f) * a;
    if (ay > ax) r = 1.57079637f - r;
    if (X < 0.f) r = 3.14159274f - r;
    return copysignf(r, Y);
}

// ---------------- Cooperative single-kernel path ----------------
// Phase 1: scan (inst kept IN REGISTERS, packed u8) -> masks + sublists.
// Phase 2: blocks<768 gather+bmax partials (+has/M/glist/gt_centers at cb==0);
//          ALL blocks then stream their 7168-f4 chunk of the zero channels.
// Phase 3: every block writes its 4096 px of ch0..5 from registers + sparse list.
__global__ __launch_bounds__(256, 5) void k_coop(const int4* __restrict__ inst4,
                                                 const float* __restrict__ centers,
                                                 int* __restrict__ ws,
                                                 float* __restrict__ out) {
    __shared__ float2 s_c2[NCEN];
    __shared__ float s_g[KS];
    __shared__ unsigned sm[4];
    __shared__ int s_loc[BCAP];
    __shared__ int s_lcnt;
    __shared__ int s_list[GCAP];
    __shared__ int s_tot;
    __shared__ float s_red[4];
    __shared__ int s_fl[FCAP];
    __shared__ int s_fM;
    __shared__ unsigned s_bm;

    cg::grid_group grid = cg::this_grid();
    int t = threadIdx.x;
    int blk = blockIdx.x;
    int b = blk / BLKS_PER_B;
    int lblk = blk - b * BLKS_PER_B;

    // ---- Phase 1: scan ----
    if (t < 4) sm[t] = 0;
    if (t == 0) s_lcnt = 0;
    if (t < KS) s_g[t] = g_G[t];
    for (int k = t; k < NCEN; k += 256)
        s_c2[k] = ((const float2*)centers)[b * NCEN + k];   // (.x=cy, .y=cx)
    __syncthreads();

    unsigned m0 = 0, m1 = 0, m2 = 0, m3 = 0;
    unsigned pk[4];                         // packed u8 insts, live across syncs
    size_t base = (size_t)blk * 1024 + t;   // int4 units
    int ppb = lblk * 4096 + t * 4;          // px offset within batch, q=0
#pragma unroll
    for (int q = 0; q < 4; q++) {
        int4 v = inst4[base + (size_t)q * 256];
        pk[q] = ((unsigned)v.x & 255u) | (((unsigned)v.y & 255u) << 8) |
                (((unsigned)v.z & 255u) << 16) | (((unsigned)v.w & 255u) << 24);
        int pp = ppb + q * 1024;
        int i = pp / NW;
        int j0 = pp - i * NW;               // 4 px never straddle a row (4|768)
        int a[4] = {v.x, v.y, v.z, v.w};
#pragma unroll
        for (int e = 0; e < 4; e++) {
            int iv = a[e];
            if (iv > 0) {
                unsigned bit = 1u << (iv & 31);
                int w = iv >> 5;
                if (w == 0) m0 |= bit; else if (w == 1) m1 |= bit;
                else if (w == 2) m2 |= bit; else m3 |= bit;
                int idx = iv - 1;
                idx = idx > NCEN - 1 ? NCEN - 1 : idx;
                float2 c = s_c2[idx];
                if (fabsf(c.y - (float)i) < 3.f && fabsf(c.x - (float)(j0 + e)) < 3.f) {
                    int slot = atomicAdd(&s_lcnt, 1);  // LDS only
                    if (slot < BCAP) s_loc[slot] = (i << 16) | (j0 + e);
                }
            }
        }
    }
#pragma unroll
    for (int off = 32; off >= 1; off >>= 1) {
        m0 |= __shfl_xor(m0, off);
        m1 |= __shfl_xor(m1, off);
        m2 |= __shfl_xor(m2, off);
        m3 |= __shfl_xor(m3, off);
    }
    if ((t & 63) == 0) {
        if (m0) atomicOr(&sm[0], m0);
        if (m1) atomicOr(&sm[1], m1);
        if (m2) atomicOr(&sm[2], m2);
        if (m3) atomicOr(&sm[3], m3);
    }
    __syncthreads();
    if (t < 4) ws[OFF_MASKS + blk * 4 + t] = (int)sm[t];
    {
        int cnt = s_lcnt < BCAP ? s_lcnt : BCAP;
        int* slot = &ws[OFF_BLIST + blk * BSLOT];
        if (t == 0) slot[0] = cnt;
        if (t < cnt) slot[1 + t] = s_loc[t];
    }
    __threadfence();
    grid.sync();

    // ---- Phase 2: bmax (blocks < 768) then zero-channel streaming (all) ----
    if (blk < NB * CAND_BLKS) {
        int b2 = blk / CAND_BLKS;
        int cb = blk - b2 * CAND_BLKS;
        if (t == 0) s_tot = 0;
        if (t < 4) sm[t] = 0;
        __syncthreads();
        if (t < BLKS_PER_B) {
            const int* slot = &ws[OFF_BLIST + (b2 * BLKS_PER_B + t) * BSLOT];
            int cnt = slot[0];
            cnt = cnt < 0 ? 0 : (cnt > BCAP ? BCAP : cnt);
            int basep = atomicAdd(&s_tot, cnt);   // LDS; order irrelevant
            for (int i2 = 0; i2 < cnt; i2++) {
                int s = basep + i2;
                if (s < GCAP) s_list[s] = slot[1 + i2];
            }
            if (cb == 0) {
                const unsigned* pm = (const unsigned*)&ws[OFF_MASKS + (b2 * BLKS_PER_B + t) * 4];
                unsigned w0 = pm[0], w1 = pm[1], w2 = pm[2], w3 = pm[3];
                if (w0) atomicOr(&sm[0], w0);
                if (w1) atomicOr(&sm[1], w1);
                if (w2) atomicOr(&sm[2], w2);
                if (w3) atomicOr(&sm[3], w3);
            }
        }
        __syncthreads();
        int M = s_tot < GCAP ? s_tot : GCAP;

        if (cb == 0) {
            float* gt = out + (size_t)NB * 13 * NHW;
            if (t < NCEN) {   // gt_centers
                float vx = 0.f, vy = 0.f;
                if (t >= 1 && ((sm[t >> 5] >> (t & 31)) & 1u)) {
                    vx = centers[(b2 * NCEN + (t - 1)) * 2 + 1];
                    vy = centers[(b2 * NCEN + (t - 1)) * 2 + 0];
                }
                gt[(b2 * NCEN + t) * 2 + 0] = vx;
                gt[(b2 * NCEN + t) * 2 + 1] = vy;
            }
            if (t == 0) {
                unsigned any = (sm[0] & 0xFFFFFFFEu) | sm[1] | sm[2] | sm[3];
                ws[OFF_HAS + b2] = any ? 1 : 0;
                ws[OFF_M + b2] = M;
            }
            for (int e = t; e < M; e += 256) ws[OFF_GLIST + b2 * GCAP + e] = s_list[e];
        }

        // bmax partial over M*441 candidate px (blur==0 elsewhere)
        float lmax = 0.f;
        int total = M * (KS * KS);
        for (int c = blk * 256 - b2 * CAND_BLKS * 256 + t; c < total; c += CAND_BLKS * 256) {
            int m = c / (KS * KS), r = c - m * (KS * KS);
            int e = s_list[m];
            int pi = (e >> 16) + r / KS - RAD;
            int pj = (e & 0xFFFF) + (r - (r / KS) * KS) - RAD;
            if (pi < 0 || pi >= NH || pj < 0 || pj >= NW) continue;
            float acc = 0.f;
            for (int m2 = 0; m2 < M; m2++) {
                int e2 = s_list[m2];
                float wi = wfun(pi, e2 >> 16, s_g);
                if (wi == 0.f) continue;
                acc += wi * wfun(pj, e2 & 0xFFFF, s_g);
            }
            lmax = fmaxf(lmax, acc);
        }
#pragma unroll
        for (int off = 32; off >= 1; off >>= 1) lmax = fmaxf(lmax, __shfl_down(lmax, off));
        if ((t & 63) == 0) s_red[t >> 6] = lmax;
        __syncthreads();
        if (t == 0) {
            float bmx = fmaxf(fmaxf(s_red[0], s_red[1]), fmaxf(s_red[2], s_red[3]));
            ((float*)ws)[OFF_BMAXP + b2 * CAND_BLKS + blk - b2 * CAND_BLKS] = bmx;
        }
    }
    {   // zero channels 6..12: every block streams one contiguous 7168-f4 chunk
        const f4 z = {0.f, 0.f, 0.f, 0.f};
        int rem0 = lblk * ZPB;              // 144 blocks/batch * 7168 = 7ch plane set
        f4* dst = (f4*)(out + (size_t)b * 13 * NHW + (size_t)6 * NHW) + rem0 + t;
#pragma unroll
        for (int it = 0; it < ZIT; ++it) STORE(z, dst + it * 256);
    }
    __threadfence();
    grid.sync();

    // ---- Phase 3: channels 0..5 from registers + sparse list ----
    if (t == 255) s_fM = 0;
    if (t == 254) s_bm = 0;
    __syncthreads();
    int has = ws[OFF_HAS + b];
    int M3 = ws[OFF_M + b];
    if (t < CAND_BLKS)   // reduce bmax partials (floats >= 0: uint compare ok)
        atomicMax(&s_bm, __float_as_uint(((const float*)ws)[OFF_BMAXP + b * CAND_BLKS + t]));
    int pp0 = lblk * 4096;
    int ri0 = pp0 / NW, ri1 = (pp0 + 4095) / NW;
    const int* gl = &ws[OFF_GLIST + b * GCAP];
    for (int m = t; m < M3; m += 256) {
        int e = gl[m];
        int qi = e >> 16;
        if (qi >= ri0 - RAD && qi <= ri1 + RAD) {   // exact superset incl. reflect
            int slot = atomicAdd(&s_fM, 1);
            if (slot < FCAP) s_fl[slot] = e;
        }
    }
    __syncthreads();
    int FM = s_fM < FCAP ? s_fM : FCAP;
    float sc = (has && M3 > 0) ? 1.f / fmaxf(__uint_as_float(s_bm), 1e-12f) : 0.f;
    float* outb = out + (size_t)b * 13 * NHW;

#pragma unroll
    for (int q = 0; q < 4; q++) {
        int pp = ppb + q * 1024;
        int gi = pp / NW;
        int gj0 = pp - gi * NW;
        unsigned v8 = pk[q];
        int ia[4] = {(int)(v8 & 255u), (int)((v8 >> 8) & 255u),
                     (int)((v8 >> 16) & 255u), (int)(v8 >> 24)};
        f4 vR, vTh, vS, vC, vIg;
#pragma unroll
        for (int e = 0; e < 4; e++) {
            int iv = ia[e];
            bool valid = iv > 0;
            int idx = iv - 1;
            idx = idx < 0 ? 0 : idx;
            float2 c = s_c2[idx];
            float gcx = valid ? c.y : -10000.f;
            float gcy = valid ? c.x : -10000.f;
            float X = gcx - (float)gi;
            float Y = gcy - (float)(gj0 + e);
            bool near = (fabsf(X) < 3.f) && (fabsf(Y) < 3.f);
            vIg[e] = near ? 0.f : 1.f;      // exact for has==0 too (near=false)
            float m = valid ? 1.f : 0.f;
            float R2 = X * X + Y * Y;
            vR[e] = sqrtf(R2) * m;
            float rinv = R2 > 0.f ? rsqrtf(R2) : 0.f;
            vS[e] = valid ? Y * rinv : 0.f;                   // sin(atan2) masked
            vC[e] = valid ? (R2 > 0.f ? X * rinv : 1.f) : 0.f;
            vTh[e] = has ? fatan2(Y, X) : 0.f;
        }
        f4 blur = {0.f, 0.f, 0.f, 0.f};
        for (int m = 0; m < FM; m++) {
            int e2 = s_fl[m];
            float wi = wfun(gi, e2 >> 16, s_g);
            if (wi == 0.f) continue;
            int qj = e2 & 0xFFFF;
#pragma unroll
            for (int e = 0; e < 4; e++) blur[e] += wi * wfun(gj0 + e, qj, s_g);
        }
        f4 vCm = blur * sc;
        STORE(vR,  (f4*)&outb[(size_t)0 * NHW + pp]);
        STORE(vTh, (f4*)&outb[(size_t)1 * NHW + pp]);
        STORE(vS,  (f4*)&outb[(size_t)2 * NHW + pp]);
        STORE(vC,  (f4*)&outb[(size_t)3 * NHW + pp]);
        STORE(vIg, (f4*)&outb[(size_t)4 * NHW + pp]);
        STORE(vCm, (f4*)&outb[(size_t)5 * NHW + pp]);
    }
}

// ---------------- Fallback 3-kernel path (R4-equivalent, proven 271.9) ----------------
__global__ __launch_bounds__(256) void k_scan_fb(const int4* __restrict__ inst4,
                                                 const float* __restrict__ centers,
                                                 int* __restrict__ ws) {
    __shared__ unsigned sm[4];
    __shared__ float2 s_c2[NCEN];
    __shared__ int s_loc[BCAP];
    __shared__ int s_lcnt;
    int t = threadIdx.x, blk = blockIdx.x;
    int b = blk / BLKS_PER_B, lblk = blk - b * BLKS_PER_B;
    if (t < 4) sm[t] = 0;
    if (t == 0) s_lcnt = 0;
    for (int k = t; k < NCEN; k += 256)
        s_c2[k] = ((const float2*)centers)[b * NCEN + k];
    __syncthreads();
    unsigned m0 = 0, m1 = 0, m2 = 0, m3 = 0;
    size_t base = (size_t)blk * 1024 + t;
    int ppb = lblk * 4096 + t * 4;
#pragma unroll
    for (int q = 0; q < 4; q++) {
        int4 v = inst4[base + (size_t)q * 256];
        int pp = ppb + q * 1024;
        int i = pp / NW, j0 = pp - (pp / NW) * NW;
        int a[4] = {v.x, v.y, v.z, v.w};
#pragma unroll
        for (int e = 0; e < 4; e++) {
            int iv = a[e];
            if (iv > 0) {
                unsigned bit = 1u << (iv & 31);
                int w = iv >> 5;
                if (w == 0) m0 |= bit; else if (w == 1) m1 |= bit;
                else if (w == 2) m2 |= bit; else m3 |= bit;
                int idx = iv - 1;
                idx = idx > NCEN - 1 ? NCEN - 1 : idx;
                float2 c = s_c2[idx];
                if (fabsf(c.y - (float)i) < 3.f && fabsf(c.x - (float)(j0 + e)) < 3.f) {
                    int slot = atomicAdd(&s_lcnt, 1);
                    if (slot < BCAP) s_loc[slot] = (i << 16) | (j0 + e);
                }
            }
        }
    }
#pragma unroll
    for (int off = 32; off >= 1; off >>= 1) {
        m0 |= __shfl_xor(m0, off); m1 |= __shfl_xor(m1, off);
        m2 |= __shfl_xor(m2, off); m3 |= __shfl_xor(m3, off);
    }
    if ((t & 63) == 0) {
        if (m0) atomicOr(&sm[0], m0);
        if (m1) atomicOr(&sm[1], m1);
        if (m2) atomicOr(&sm[2], m2);
        if (m3) atomicOr(&sm[3], m3);
    }
    __syncthreads();
    if (t < 4) ws[OFF_MASKS + blk * 4 + t] = (int)sm[t];
    int cnt = s_lcnt < BCAP ? s_lcnt : BCAP;
    int* slot = &ws[OFF_BLIST + blk * BSLOT];
    if (t == 0) slot[0] = cnt;
    if (t < cnt) slot[1 + t] = s_loc[t];
}

__global__ __launch_bounds__(256) void k_mid_fb(const float* __restrict__ centers,
                                                int* __restrict__ ws,
                                                float* __restrict__ out) {
    int t = threadIdx.x, g = blockIdx.x;
    if (g < NB * CAND_BLKS) {
        __shared__ float s_g[KS];
        __shared__ int s_list[GCAP];
        __shared__ int s_tot;
        __shared__ unsigned s_m[4];
        __shared__ float s_red[4];
        int b = g / CAND_BLKS, cb = g - b * CAND_BLKS;
        if (t < KS) s_g[t] = g_G[t];
        if (t == 0) s_tot = 0;
        if (t < 4) s_m[t] = 0;
        __syncthreads();
        if (t < BLKS_PER_B) {
            const int* slot = &ws[OFF_BLIST + (b * BLKS_PER_B + t) * BSLOT];
            int cnt = slot[0];
            cnt = cnt < 0 ? 0 : (cnt > BCAP ? BCAP : cnt);
            int basep = atomicAdd(&s_tot, cnt);
            for (int i2 = 0; i2 < cnt; i2++) {
                int s = basep + i2;
                if (s < GCAP) s_list[s] = slot[1 + i2];
            }
            if (cb == 0) {
                const unsigned* pm = (const unsigned*)&ws[OFF_MASKS + (b * BLKS_PER_B + t) * 4];
                if (pm[0]) atomicOr(&s_m[0], pm[0]);
                if (pm[1]) atomicOr(&s_m[1], pm[1]);
                if (pm[2]) atomicOr(&s_m[2], pm[2]);
                if (pm[3]) atomicOr(&s_m[3], pm[3]);
            }
        }
        __syncthreads();
        int M = s_tot < GCAP ? s_tot : GCAP;
        if (cb == 0) {
            float* gt = out + (size_t)NB * 13 * NHW;
            if (t < NCEN) {
                float vx = 0.f, vy = 0.f;
                if (t >= 1 && ((s_m[t >> 5] >> (t & 31)) & 1u)) {
                    vx = centers[(b * NCEN + (t - 1)) * 2 + 1];
                    vy = centers[(b * NCEN + (t - 1)) * 2 + 0];
                }
                gt[(b * NCEN + t) * 2 + 0] = vx;
                gt[(b * NCEN + t) * 2 + 1] = vy;
            }
            if (t == 0) {
                unsigned any = (s_m[0] & 0xFFFFFFFEu) | s_m[1] | s_m[2] | s_m[3];
                ws[OFF_HAS + b] = any ? 1 : 0;
                ws[OFF_M + b] = M;
            }
            for (int e = t; e < M; e += 256) ws[OFF_GLIST + b * GCAP + e] = s_list[e];
        }
        float lmax = 0.f;
        int total = M * (KS * KS);
        for (int c = cb * 256 + t; c < total; c += CAND_BLKS * 256) {
            int m = c / (KS * KS), r = c - m * (KS * KS);
            int e = s_list[m];
            int pi = (e >> 16) + r / KS - RAD;
            int pj = (e & 0xFFFF) + (r - (r / KS) * KS) - RAD;
            if (pi < 0 || pi >= NH || pj < 0 || pj >= NW) continue;
            float acc = 0.f;
            for (int m2 = 0; m2 < M; m2++) {
                int e2 = s_list[m2];
                float wi = wfun(pi, e2 >> 16, s_g);
                if (wi == 0.f) continue;
                acc += wi * wfun(pj, e2 & 0xFFFF, s_g);
            }
            lmax = fmaxf(lmax, acc);
        }
#pragma unroll
        for (int off = 32; off >= 1; off >>= 1) lmax = fmaxf(lmax, __shfl_down(lmax, off));
        if ((t & 63) == 0) s_red[t >> 6] = lmax;
        __syncthreads();
        if (t == 0) {
            float bmx = fmaxf(fmaxf(s_red[0], s_red[1]), fmaxf(s_red[2], s_red[3]));
            ((float*)ws)[OFF_BMAXP + b * CAND_BLKS + cb] = bmx;
        }
    } else {
        int zblk = g - NB * CAND_BLKS;          // [0, 1344)
        int b2 = zblk / 168;
        int rem0 = (zblk - b2 * 168) * 6144;
        const f4 z = {0.f, 0.f, 0.f, 0.f};
        f4* dst = (f4*)out + (size_t)b2 * (13 * NHW / 4) + (6 * NHW / 4) + rem0 + t;
#pragma unroll
        for (int it = 0; it < 24; ++it) STORE(z, dst + it * 256);
    }
}

__global__ __launch_bounds__(256) void k_fused_fb(const int* __restrict__ inst,
                                                  const float* __restrict__ centers,
                                                  const int* __restrict__ ws,
                                                  float* __restrict__ out) {
    __shared__ float s_cen[2 * NCEN];
    __shared__ float s_g[KS];
    __shared__ int s_fl[FCAP];
    __shared__ int s_fM;
    __shared__ unsigned s_bm;
    int t = threadIdx.x;
    int b = blockIdx.x / (NHW / 3072);
    int qblk = blockIdx.x - b * (NHW / 3072);
    int has = ws[OFF_HAS + b];
    int M = ws[OFF_M + b];
    for (int k = t; k < 2 * NCEN; k += 256) s_cen[k] = centers[b * 2 * NCEN + k];
    if (t < KS) s_g[t] = g_G[t];
    if (t == 255) s_fM = 0;
    if (t == 254) s_bm = 0;
    __syncthreads();
    if (t < CAND_BLKS)
        atomicMax(&s_bm, __float_as_uint(((const float*)ws)[OFF_BMAXP + b * CAND_BLKS + t]));
    int p0blk = qblk * 3072;
    int r0 = qblk * 4;
    const int* gl = &ws[OFF_GLIST + b * GCAP];
    for (int m = t; m < M; m += 256) {
        int e = gl[m];
        int qi = e >> 16;
        if (qi >= r0 - RAD && qi <= r0 + 3 + RAD) {
            int slot = atomicAdd(&s_fM, 1);
            if (slot < FCAP) s_fl[slot] = e;
        }
    }
    __syncthreads();
    int FM = s_fM < FCAP ? s_fM : FCAP;
    float sc = (has && M > 0) ? 1.f / fmaxf(__uint_as_float(s_bm), 1e-12f) : 0.f;
    float* outb = out + (size_t)b * 13 * NHW;
    for (int qq = 0; qq < 3; ++qq) {
        int p0 = p0blk + qq * 1024 + t * 4;
        int gi = p0 / NW, gj0 = p0 - (p0 / NW) * NW;
        int4 ivv = *(const int4*)&inst[(size_t)b * NHW + p0];
        int ia[4] = {ivv.x, ivv.y, ivv.z, ivv.w};
        f4 vR, vTh, vS, vC, vIg;
#pragma unroll
        for (int e = 0; e < 4; e++) {
            int iv = ia[e];
            bool valid = iv > 0;
            int idx = iv - 1;
            idx = idx < 0 ? 0 : idx;
            float cy = s_cen[2 * idx], cx = s_cen[2 * idx + 1];
            float X = (valid ? cx : -10000.f) - (float)gi;
            float Y = (valid ? cy : -10000.f) - (float)(gj0 + e);
            bool near = (fabsf(X) < 3.f) && (fabsf(Y) < 3.f);
            vIg[e] = near ? 0.f : 1.f;
            float m = valid ? 1.f : 0.f;
            float R2 = X * X + Y * Y;
            vR[e] = sqrtf(R2) * m;
            float rinv = R2 > 0.f ? rsqrtf(R2) : 0.f;
            vS[e] = valid ? Y * rinv : 0.f;
            vC[e] = valid ? (R2 > 0.f ? X * rinv : 1.f) : 0.f;
            vTh[e] = has ? fatan2(Y, X) : 0.f;
        }
        f4 blur = {0.f, 0.f, 0.f, 0.f};
        for (int m = 0; m < FM; m++) {
            int e2 = s_fl[m];
            float wi = wfun(gi, e2 >> 16, s_g);
            if (wi == 0.f) continue;
            int qj = e2 & 0xFFFF;
#pragma unroll
            for (int e = 0; e < 4; e++) blur[e] += wi * wfun(gj0 + e, qj, s_g);
        }
        f4 vCm = blur * sc;
        STORE(vR,  (f4*)&outb[(size_t)0 * NHW + p0]);
        STORE(vTh, (f4*)&outb[(size_t)1 * NHW + p0]);
        STORE(vS,  (f4*)&outb[(size_t)2 * NHW + p0]);
        STORE(vC,  (f4*)&outb[(size_t)3 * NHW + p0]);
        STORE(vIg, (f4*)&outb[(size_t)4 * NHW + p0]);
        STORE(vCm, (f4*)&outb[(size_t)5 * NHW + p0]);
    }
}

extern "C" void kernel_launch(void* const* d_in, const int* in_sizes, int n_in,
                              void* d_out, int out_size, void* d_ws, size_t ws_size,
                              hipStream_t stream) {
    const int* inst = (const int*)d_in[0];
    const float* centers = (const float*)d_in[1];
    float* out = (float*)d_out;
    int* ws = (int*)d_ws;

    static int coop = -1;
    if (coop < 0) {
        int dev = 0, v = 0;
        hipGetDevice(&dev);
        hipDeviceGetAttribute(&v, hipDeviceAttributeCooperativeLaunch, dev);
        coop = v ? 1 : 0;
    }
    if (coop) {
        const int4* inst4 = (const int4*)inst;
        void* args[] = {(void*)&inst4, (void*)&centers, (void*)&ws, (void*)&out};
        hipError_t err = hipLaunchCooperativeKernel((const void*)k_coop,
                                                    dim3(SCAN_BLKS), dim3(256),
                                                    args, 0, stream);
        if (err == hipSuccess) return;
        coop = 0;   // fall through once, then stick to fallback
    }
    k_scan_fb<<<SCAN_BLKS, 256, 0, stream>>>((const int4*)inst, centers, ws);
    k_mid_fb<<<NB * CAND_BLKS + 1344, 256, 0, stream>>>(centers, ws, out);
    k_fused_fb<<<NB * (NHW / 3072), 256, 0, stream>>>(inst, centers, ws, out);
}